// Round 12
// baseline (9802.705 us; speedup 1.0000x reference)
//
#include <hip/hip_runtime.h>
#include <hip/hip_fp16.h>
#include <math.h>

#define BB    64
#define TT    2048
#define DIN   128
#define HH    512
#define NWG   256
#define NTHR  256

typedef __attribute__((ext_vector_type(4))) unsigned int u32x4;
typedef __attribute__((ext_vector_type(8))) _Float16    f16x8;
typedef __attribute__((ext_vector_type(4))) float       f32x4;
typedef unsigned long long u64;

__device__ __forceinline__ float sigm(float v) { return 1.0f / (1.0f + expf(-v)); }

// ---- MALL (agent-scope) primitives — proven protocol ----
__device__ __forceinline__ u64 ald(const void* p) {
  return __hip_atomic_load((const u64*)p, __ATOMIC_RELAXED, __HIP_MEMORY_SCOPE_AGENT);
}
__device__ __forceinline__ void ast(void* p, u64 v) {
  __hip_atomic_store((u64*)p, v, __ATOMIC_RELAXED, __HIP_MEMORY_SCOPE_AGENT);
}
__device__ __forceinline__ void put16(char* dst, u64 lo, u64 hi) {
  u32x4 v; v.x=(unsigned)lo; v.y=(unsigned)(lo>>32); v.z=(unsigned)hi; v.w=(unsigned)(hi>>32);
  *reinterpret_cast<u32x4*>(dst) = v;
}
__device__ __forceinline__ void barrive(unsigned* cnt) {
  __hip_atomic_fetch_add(cnt, 1u, __ATOMIC_RELAXED, __HIP_MEMORY_SCOPE_AGENT);
}
__device__ __forceinline__ void bpoll(unsigned* cnt, unsigned target, int* dead) {
  if (*dead) return;
  long sp = 0;
  while (__hip_atomic_load(cnt, __ATOMIC_RELAXED, __HIP_MEMORY_SCOPE_AGENT) < target) {
    __builtin_amdgcn_s_sleep(1);
    if (++sp > (1L << 22)) { *dead = 1; break; }   // no-hang valve
  }
}

// ---- prep kernels -----------------------------------------------------------
__global__ __launch_bounds__(64, 1) void prep_flush() {
  extern __shared__ char dummy[];
  if (threadIdx.x == 0) { __threadfence(); dummy[0] = 0; }
  __syncthreads();
}
__global__ void prep_zero(unsigned* w) {
  const int total = (131072 + 196608 + 4096) / 4;   // h0(2 buf) + h1(3 buf) + barrier words
  for (int i = blockIdx.x*blockDim.x + threadIdx.x; i < total; i += gridDim.x*blockDim.x)
    __hip_atomic_store(w + i, 0u, __ATOMIC_RELAXED, __HIP_MEMORY_SCOPE_AGENT);
}
__global__ void xcvt(const float* __restrict__ x, u64* __restrict__ xh) {
  const int N4 = BB*TT*DIN/4;
  const float4* x4 = reinterpret_cast<const float4*>(x);
  for (int i = blockIdx.x*blockDim.x + threadIdx.x; i < N4; i += gridDim.x*blockDim.x) {
    float4 v = x4[i];
    __half2 a = __floats2half2_rn(v.x, v.y);
    __half2 b = __floats2half2_rn(v.z, v.w);
    u64 u = ((u64)__builtin_bit_cast(unsigned, b) << 32) | (u64)__builtin_bit_cast(unsigned, a);
    __hip_atomic_store(&xh[i], u, __ATOMIC_RELAXED, __HIP_MEMORY_SCOPE_AGENT);
  }
}

__global__ __launch_bounds__(NTHR, 1) void lstm2_lp2(
    const float* __restrict__ Wih0, const float* __restrict__ Whh0,
    const float* __restrict__ bih0, const float* __restrict__ bhh0,
    const float* __restrict__ Wih1, const float* __restrict__ Whh1,
    const float* __restrict__ bih1, const float* __restrict__ bhh1,
    const float* __restrict__ fcw,  const float* __restrict__ fcb,
    float* __restrict__ out, float* __restrict__ ws)
{
  extern __shared__ char smbase[];
  char* buf0 = smbase;             // LDS staging buffer parity 0 (1152 x 16B)
  char* buf1 = smbase + 18432;     // parity 1
  __half* hout = reinterpret_cast<__half*>(smbase + 36864);  // [2][8][16]
  int*    dead = reinterpret_cast<int*>(smbase + 37376);

  const int tid  = threadIdx.x;
  const int wg   = blockIdx.x;
  const int lane = tid & 63;
  const int wv   = tid >> 6;
  const int grp  = wg >> 5;        // batch group (8 rows)
  const int r    = wg & 31;        // rank -> h-cols [16r,16r+16)
  const int bg8  = grp * 8;
  const int c0   = 16*r + 4*wv;

  __half* h0s = reinterpret_cast<__half*>(ws);                       // 2 x [64][512]
  __half* h1s = reinterpret_cast<__half*>((char*)ws + 131072);       // 3 x [64][512]
  unsigned* barb = reinterpret_cast<unsigned*>((char*)ws + 327680);
  unsigned* gA = barb + grp*32;
  unsigned* gB = barb + 512 + grp*32;
  const __half* xh = reinterpret_cast<const __half*>((char*)ws + 524288);

  // A-fragments, rt = jc*4 + gate (transpose-free epilogue, verified r10)
  const int rt   = lane & 15;
  const int gate = rt & 3;
  const int jc   = rt >> 2;
  const int kg   = lane >> 4;
  const int b15  = lane & 15;
  const int n0   = gate*HH + (c0 + jc);

  f16x8 af0[20];   // L0: K=640 = [x 0-127 | h0 128-639]
#pragma unroll
  for (int m = 0; m < 20; ++m) {
    int k0 = 32*m + 8*kg;
    const float* srcp = (k0 < DIN) ? (Wih0 + (size_t)n0*DIN + k0)
                                   : (Whh0 + (size_t)n0*HH + (k0 - DIN));
    float4 a = *reinterpret_cast<const float4*>(srcp);
    float4 b = *reinterpret_cast<const float4*>(srcp + 4);
    f16x8 fr;
    fr[0]=(_Float16)a.x; fr[1]=(_Float16)a.y; fr[2]=(_Float16)a.z; fr[3]=(_Float16)a.w;
    fr[4]=(_Float16)b.x; fr[5]=(_Float16)b.y; fr[6]=(_Float16)b.z; fr[7]=(_Float16)b.w;
    af0[m] = fr;
  }
  f16x8 af1[32];   // L1: K=1024 = [h0 (W_ih1) | h1 (W_hh1)]
#pragma unroll
  for (int m = 0; m < 32; ++m) {
    int k0 = 32*m + 8*kg;
    const float* srcp = (k0 < HH) ? (Wih1 + (size_t)n0*HH + k0)
                                  : (Whh1 + (size_t)n0*HH + (k0 - HH));
    float4 a = *reinterpret_cast<const float4*>(srcp);
    float4 b = *reinterpret_cast<const float4*>(srcp + 4);
    f16x8 fr;
    fr[0]=(_Float16)a.x; fr[1]=(_Float16)a.y; fr[2]=(_Float16)a.z; fr[3]=(_Float16)a.w;
    fr[4]=(_Float16)b.x; fr[5]=(_Float16)b.y; fr[6]=(_Float16)b.z; fr[7]=(_Float16)b.w;
    af1[m] = fr;
  }

  const int cmy = c0 + kg;
  float bv0[4], bv1[4];
#pragma unroll
  for (int g = 0; g < 4; ++g) {
    bv0[g] = bih0[g*HH + cmy] + bhh0[g*HH + cmy];
    bv1[g] = bih1[g*HH + cmy] + bhh1[g*HH + cmy];
  }

  float cst0 = 0.f, cst1 = 0.f;
  const int beff = (b15 < 8) ? b15 : 7;
  if (tid == 0) *dead = 0;

  // prologue: stage x(0) into buf0 x-region
  if (tid < 128) {
    int b = tid >> 4, u = tid & 15;
    const __half* s_ = xh + (size_t)(bg8+b)*TT*DIN + (size_t)0*DIN + u*8;
    u64 lo = ald(s_), hi = ald(s_ + 4);
    put16(buf0 + (b*16 + (u^b))*16, lo, hi);
  }
  __syncthreads();

  // Pipeline (1-deeper than r11, fixing its stale-h0 bug):
  //   computeA(st) = L0 time st        (st < TT)
  //   computeB(st) = L1 time st-2      (st >= 2)  — inputs h0(st-2), h1(st-3),
  //     both staged in bufp during iteration st-1. Full L1 overlap of h0-load RT.
  for (int st = 0; st <= TT + 1; ++st) {
    char* bufc = (st & 1) ? buf1 : buf0;   // cur
    char* bufp = (st & 1) ? buf0 : buf1;   // prev

    // ---- pollA: h0(st-1) globally ready (arriveA is unconditional/iter) ----
    if (tid == 0) bpoll(gA, 32u*(unsigned)st, dead);
    __syncthreads();

    // ---- issue loadsA: h0(st-1) (parity st&1), 2 units/thread ----
    const __half* h0r = h0s + (size_t)(st & 1)*BB*HH;
    u64 a0, a1, a2, a3;
    { int idx = tid;       int b = idx>>6, u = idx&63;
      const __half* s_ = h0r + (size_t)(bg8+b)*HH + u*8; a0 = ald(s_); a1 = ald(s_+4); }
    { int idx = tid + 256; int b = idx>>6, u = idx&63;
      const __half* s_ = h0r + (size_t)(bg8+b)*HH + u*8; a2 = ald(s_); a3 = ald(s_+4); }
    __builtin_amdgcn_sched_barrier(0);   // pin load issue before computeB

    // ---- computeB(st): L1 time st-2 from bufp (overlaps h0-load latency) ----
    if (st >= 2) {
      f32x4 p1a = {0.f,0.f,0.f,0.f}, p1b = p1a;
#pragma unroll
      for (int m = 0; m < 32; ++m) {
        int phys = (m < 16) ? (128 + beff*64 + ((4*m + kg) ^ beff))
                            : (640 + beff*64 + ((4*(m-16) + kg) ^ beff));
        f16x8 bf = *reinterpret_cast<const f16x8*>(bufp + phys*16);
        if (m & 1) p1b = __builtin_amdgcn_mfma_f32_16x16x32_f16(af1[m], bf, p1b, 0, 0, 0);
        else       p1a = __builtin_amdgcn_mfma_f32_16x16x32_f16(af1[m], bf, p1a, 0, 0, 0);
      }
      f32x4 av = p1a + p1b;
      float gi = sigm (av[0] + bv1[0]);
      float gf = sigm (av[1] + bv1[1]);
      float gg = tanhf(av[2] + bv1[2]);
      float go = sigm (av[3] + bv1[3]);
      cst1 = gf*cst1 + gi*gg;
      float hn = go * tanhf(cst1);
      if (b15 < 8) hout[(8 + b15)*16 + 4*wv + kg] = __float2half(hn);
    }
    __syncthreads();
    if (st >= 2 && tid < 32) {           // pack-store h1(st-2) -> mod-3 buf (st-2)%3
      int b = tid >> 2, part = tid & 3;
      u64 v = *reinterpret_cast<u64*>(hout + (8 + b)*16 + part*4);
      __half* base = h1s + (size_t)((st + 1) % 3)*BB*HH;
      ast(base + (size_t)(bg8+b)*HH + 16*r + part*4, v);
    }

    // ---- stage h0(st-1) -> LDS[cur] (compiler waits a0..a3) ----
    { int idx = tid;       int b = idx>>6, u = idx&63;
      put16(bufc + (128 + b*64 + (u^b))*16, a0, a1); }
    { int idx = tid + 256; int b = idx>>6, u = idx&63;
      put16(bufc + (128 + b*64 + (u^b))*16, a2, a3); }
    asm volatile("s_waitcnt vmcnt(0)" ::: "memory");   // h1 pack-stores MALL-ack'd
    if (tid == 0 && st >= 2) barrive(gB);
    __syncthreads();

    // ---- computeA(st): L0 time st from bufc (x(st), h0(st-1)) ----
    if (st < TT) {
      f32x4 p0a = {0.f,0.f,0.f,0.f}, p0b = p0a;
#pragma unroll
      for (int m = 0; m < 20; ++m) {
        int phys = (m < 4) ? (beff*16 + ((4*m + kg) ^ beff))
                           : (128 + beff*64 + ((4*(m-4) + kg) ^ beff));
        f16x8 bf = *reinterpret_cast<const f16x8*>(bufc + phys*16);
        if (m & 1) p0b = __builtin_amdgcn_mfma_f32_16x16x32_f16(af0[m], bf, p0b, 0, 0, 0);
        else       p0a = __builtin_amdgcn_mfma_f32_16x16x32_f16(af0[m], bf, p0a, 0, 0, 0);
      }
      f32x4 av = p0a + p0b;
      float gi = sigm (av[0] + bv0[0]);
      float gf = sigm (av[1] + bv0[1]);
      float gg = tanhf(av[2] + bv0[2]);
      float go = sigm (av[3] + bv0[3]);
      cst0 = gf*cst0 + gi*gg;
      float hn = go * tanhf(cst0);
      if (b15 < 8) hout[b15*16 + 4*wv + kg] = __float2half(hn);
    }
    __syncthreads();
    if (st < TT && tid < 32) {           // pack-store h0(st) -> parity (st+1)&1
      int b = tid >> 2, part = tid & 3;
      u64 v = *reinterpret_cast<u64*>(hout + b*16 + part*4);
      __half* base = h0s + (size_t)((st+1) & 1)*BB*HH;
      ast(base + (size_t)(bg8+b)*HH + 16*r + part*4, v);
    }
    asm volatile("s_waitcnt vmcnt(0)" ::: "memory");   // h0 stores MALL-ack'd
    if (tid == 0) barrive(gA);

    // ---- pollB + end-stage: h1(st-2) -> bufc region 640, x(st+1) -> bufp x ----
    {
      unsigned tgtB = (st >= 1) ? 32u*(unsigned)(st - 1) : 0u;
      if (tid == 0) bpoll(gB, tgtB, dead);
    }
    __syncthreads();
    {
      const __half* hb = h1s + (size_t)((st + 1) % 3)*BB*HH;   // h1(st-2)
      int tx = (st+1 < TT) ? (st+1) : (TT-1);
      u64 e0, e1, e2, e3, e4 = 0, e5 = 0;
      { int idx = tid;       int b = idx>>6, u = idx&63;
        const __half* s_ = hb + (size_t)(bg8+b)*HH + u*8; e0 = ald(s_); e1 = ald(s_+4); }
      { int idx = tid + 256; int b = idx>>6, u = idx&63;
        const __half* s_ = hb + (size_t)(bg8+b)*HH + u*8; e2 = ald(s_); e3 = ald(s_+4); }
      const bool hx = (tid < 128);
      if (hx) { int b = tid>>4, u = tid&15;
        const __half* s_ = xh + (size_t)(bg8+b)*TT*DIN + (size_t)tx*DIN + u*8;
        e4 = ald(s_); e5 = ald(s_+4); }
      { int idx = tid;       int b = idx>>6, u = idx&63;
        put16(bufc + (640 + b*64 + (u^b))*16, e0, e1); }
      { int idx = tid + 256; int b = idx>>6, u = idx&63;
        put16(bufc + (640 + b*64 + (u^b))*16, e2, e3); }
      if (hx) { int b = tid>>4, u = tid&15;
        put16(bufp + (b*16 + (u^b))*16, e4, e5); }     // x(st+1) -> next iter's bufc
    }
    __syncthreads();
  }

  // ---- FC on h1(TT-1) (mod-3 buffer (TT-1)%3; pollB above covers stores) ----
  {
    const __half* h1f = h1s + (size_t)((TT-1) % 3)*BB*HH;
    int oi = tid >> 3, kp = tid & 7;
    int b  = oi >> 2, cc = oi & 3;
    int ocol = 4*r + cc;
    const u64* h8 = reinterpret_cast<const u64*>(h1f + (size_t)(bg8+b)*HH) + kp*16;
    const float* wrow = fcw + (size_t)ocol*HH + kp*64;
    float p = 0.f;
#pragma unroll
    for (int kk = 0; kk < 16; ++kk) {
      u64 v = ald(h8 + kk);
      __half2 hlo = __builtin_bit_cast(__half2, (unsigned)(v & 0xffffffffull));
      __half2 hhi = __builtin_bit_cast(__half2, (unsigned)(v >> 32));
      float2 flo = __half22float2(hlo), fhi = __half22float2(hhi);
      float4 w = *reinterpret_cast<const float4*>(wrow + kk*4);
      p += flo.x*w.x + flo.y*w.y + fhi.x*w.z + fhi.y*w.w;
    }
    p += __shfl_xor(p, 1);
    p += __shfl_xor(p, 2);
    p += __shfl_xor(p, 4);
    if (kp == 0) out[(size_t)(bg8+b)*128 + ocol] = p + fcb[ocol];
  }
}

__global__ void sentinel_fail(float* out, float v) { out[threadIdx.x] = v; }

extern "C" void kernel_launch(void* const* d_in, const int* in_sizes, int n_in,
                              void* d_out, int out_size, void* d_ws, size_t ws_size,
                              hipStream_t stream) {
  const float* x    = (const float*)d_in[0];
  const float* Wih0 = (const float*)d_in[1];
  const float* Whh0 = (const float*)d_in[2];
  const float* bih0 = (const float*)d_in[3];
  const float* bhh0 = (const float*)d_in[4];
  const float* Wih1 = (const float*)d_in[5];
  const float* Whh1 = (const float*)d_in[6];
  const float* bih1 = (const float*)d_in[7];
  const float* bhh1 = (const float*)d_in[8];
  const float* fcw  = (const float*)d_in[9];
  const float* fcb  = (const float*)d_in[10];
  float* out = (float*)d_out;
  float* ws  = (float*)d_ws;
  (void)in_sizes; (void)n_in; (void)out_size;

  const size_t need = 524288 + (size_t)BB*TT*DIN*2;
  if (ws_size < need) {
    sentinel_fail<<<1, 128, 0, stream>>>(out, 2.0e6f);
    return;
  }

  const int smem_bytes = 108*1024;   // forces 1 WG/CU
  hipFuncSetAttribute(reinterpret_cast<const void*>(&lstm2_lp2),
                      hipFuncAttributeMaxDynamicSharedMemorySize, smem_bytes);
  hipFuncSetAttribute(reinterpret_cast<const void*>(&prep_flush),
                      hipFuncAttributeMaxDynamicSharedMemorySize, smem_bytes);

  (void)hipGetLastError();
  prep_flush<<<dim3(NWG), dim3(64), smem_bytes, stream>>>();
  xcvt<<<dim3(2048), dim3(NTHR), 0, stream>>>(
      x, reinterpret_cast<u64*>(reinterpret_cast<char*>(d_ws) + 524288));
  prep_zero<<<dim3(NWG), dim3(NTHR), 0, stream>>>((unsigned*)d_ws);
  lstm2_lp2<<<dim3(NWG), dim3(NTHR), smem_bytes, stream>>>(
      Wih0, Whh0, bih0, bhh0, Wih1, Whh1, bih1, bhh1, fcw, fcb, out, ws);
  hipError_t e = hipGetLastError();
  if (e != hipSuccess) {
    sentinel_fail<<<1, 128, 0, stream>>>(out, 1.0e6f);
  }
}